// Round 7
// baseline (429.181 us; speedup 1.0000x reference)
//
#include <hip/hip_runtime.h>
#include <math.h>

// EntNet forward on MI355X.
// Sizes: VOC=32000, MEM=128, NSLOTS=20, NSENT=128, MAXLEN=32, QLEN=16, ANSLEN=8, B=64
//
// R21 = R17 skeleton (best proven: scan 188us) + in-register gate.
// Key observation: the MFMA A-fragments w[kc] that thread (wave,l32,q)
// reads each step ARE row b=bt2*32+l32's m-slice {kc*16+q*8..+7} — i.e.
// the q-pair of lanes jointly holds the ENTIRE state row. So the gate dot
// dot(s_t[b], mem[b]) = sum_kc dot(w[kc], sf[kc]) + shfl_xor(32), computed
// by waves 0/1 only (rows 0..31 / 32..63) with v_dot2_f32_bf16.
// Deleted vs R17: gate's 2x b128 AB re-reads (x8 waves), 32-op unpack/fma
// gate VALU on all 8 waves, xor1/2/4 gate reduce, the fp32 sT plane and
// its 4x float4/thread/step loads. Added: sT2 bf16 chunk-planes
// [t][chunk][b][8] so gate s-loads are 8x16B coalesced (waves 0/1 only),
// ping-ponged at step top for full-step vmcnt cover (R17 lesson).
// R20 lesson encoded: coalesced loads + proven LDS write pattern kept.

typedef __attribute__((ext_vector_type(8)))  short bf16x8;
typedef __attribute__((ext_vector_type(16))) float f32x16;

__device__ __forceinline__ unsigned short f2bh(float x) {   // f32 -> bf16 RNE
    unsigned int u = __float_as_uint(x);
    u += 0x7FFFu + ((u >> 16) & 1u);
    return (unsigned short)(u >> 16);
}
// u32 holding two bf16 (little-endian): low 16 = element 2i, high = 2i+1
__device__ __forceinline__ float blo(unsigned int w) { return __uint_as_float(w << 16); }
__device__ __forceinline__ float bhi(unsigned int w) { return __uint_as_float(w & 0xFFFF0000u); }

#if __has_builtin(__builtin_amdgcn_fdot2_f32_bf16)
typedef __attribute__((ext_vector_type(2))) __bf16 bf16x2v;
__device__ __forceinline__ float dot2bf(unsigned int a, unsigned int b, float c) {
    return __builtin_amdgcn_fdot2_f32_bf16(
        __builtin_bit_cast(bf16x2v, a), __builtin_bit_cast(bf16x2v, b), c, false);
}
#else
__device__ __forceinline__ float dot2bf(unsigned int a, unsigned int b, float c) {
    return fmaf(bhi(a), bhi(b), fmaf(blo(a), blo(b), c));
}
#endif

// butterfly add with quad-local DPP (xor1: quad_perm[1,0,3,2]=0xB1,
// xor2: quad_perm[2,3,0,1]=0x4E) — ~4cy vs ~35cy ds_swizzle.
__device__ __forceinline__ float dpp_xor1_add(float x) {
    int y = __builtin_amdgcn_update_dpp(0, __float_as_int(x), 0xB1, 0xF, 0xF, true);
    return x + __int_as_float(y);
}
__device__ __forceinline__ float dpp_xor2_add(float x) {
    int y = __builtin_amdgcn_update_dpp(0, __float_as_int(x), 0x4E, 0xF, 0xF, true);
    return x + __int_as_float(y);
}

// LDS-only workgroup barrier: waits own DS ops, does NOT drain vmcnt, so
// prefetched global loads (private register results) stay in flight.
#define LDS_BARRIER() do {                                   \
    asm volatile("s_waitcnt lgkmcnt(0)" ::: "memory");       \
    __builtin_amdgcn_s_barrier();                            \
    asm volatile("" ::: "memory");                           \
} while (0)

// ---------------------------------------------------------------- prep
__global__ __launch_bounds__(128) void prep_kernel(
    const int* __restrict__ ids, const int* __restrict__ ques, const int* __restrict__ ans,
    const float* __restrict__ E, const float* __restrict__ Ww, const float* __restrict__ Wb,
    const float* __restrict__ Vw, const float* __restrict__ Vb, const float* __restrict__ skeys,
    unsigned short* __restrict__ sT2, float* __restrict__ WsT, float* __restrict__ vkey,
    float* __restrict__ qv, float* __restrict__ a1v, float* __restrict__ a2v,
    float* __restrict__ SK)
{
    const int bi  = blockIdx.x;
    const int tid = threadIdx.x;   // 128
    __shared__ float s_l[8][132];
    __shared__ float sk_l[20 * 132];
    __shared__ float k_l[128];
    if (bi < 1024) {
        const int b = bi >> 4;
        const int g = bi & 15;
        for (int r = tid; r < 2560; r += 128) sk_l[(r >> 7) * 132 + (r & 127)] = skeys[r];
        const int chunk = tid >> 3;      // m/8
        const int elem  = tid & 7;       // m%8
        for (int tt = 0; tt < 8; ++tt) {
            const int t     = g * 8 + tt;
            const int token = ids[b * 4096 + t];
            const float v   = E[token * 128 + tid];
            s_l[tt][tid] = v;
            // chunk-planes: sT2[t][chunk][b][elem]
            sT2[((t * 16 + chunk) * 64 + b) * 8 + elem] = f2bh(v);
        }
        __syncthreads();
        // Ws rows
        float acc[8];
        const float wbn = Wb[tid];
        #pragma unroll
        for (int i = 0; i < 8; ++i) acc[i] = wbn;
        const float4* wrow = (const float4*)(Ww + tid * 128);
        for (int m4 = 0; m4 < 32; ++m4) {
            const float4 w = wrow[m4];
            #pragma unroll
            for (int tt = 0; tt < 8; ++tt) {
                acc[tt] += s_l[tt][m4*4+0]*w.x + s_l[tt][m4*4+1]*w.y
                         + s_l[tt][m4*4+2]*w.z + s_l[tt][m4*4+3]*w.w;
            }
        }
        for (int tt = 0; tt < 8; ++tt)
            WsT[((g*8+tt) * 64 + b) * 128 + tid] = acc[tt];     // layout (t, b, n)
        // SK[j][t][b] = dot(s_t[b], skeys[j])  (gate key-dot, hoisted from scan)
        for (int idx = tid; idx < 160; idx += 128) {
            const int tt = idx / 20;
            const int jj = idx - tt * 20;
            float d = 0.f;
            for (int m = 0; m < 128; ++m) d += s_l[tt][m] * sk_l[jj * 132 + m];
            SK[(jj * 128 + (g*8 + tt)) * 64 + b] = d;
        }
    } else if (bi < 1044) {
        const int j = bi - 1024;
        k_l[tid] = skeys[j * 128 + tid];
        __syncthreads();
        float acc = Vb[tid];
        const float4* vrow = (const float4*)(Vw + tid * 128);
        for (int m4 = 0; m4 < 32; ++m4) {
            const float4 w = vrow[m4];
            acc += k_l[m4*4]*w.x + k_l[m4*4+1]*w.y + k_l[m4*4+2]*w.z + k_l[m4*4+3]*w.w;
        }
        vkey[j * 128 + tid] = acc;
    } else {
        const int b = bi - 1044;
        float sq = 0.f, s1 = 0.f, s2 = 0.f;
        for (int i = 0; i < 16; ++i) sq += E[ques[b*16+i] * 128 + tid];
        for (int i = 0; i < 8;  ++i) s1 += E[ans[(b*8+i)*2+0] * 128 + tid];
        for (int i = 0; i < 8;  ++i) s2 += E[ans[(b*8+i)*2+1] * 128 + tid];
        qv [b*128+tid] = sq * (1.f/16.f);
        a1v[b*128+tid] = s1 * 0.125f;
        a2v[b*128+tid] = s2 * 0.125f;
    }
}

// ---------------------------------------------------------------- scan (MFMA 32x32, bf16 state)
// One block per slot j. 512 threads = 8 waves, 2 waves/SIMD.
// Each wave owns ONE 32x32 C tile (bt2 = wave&1, nt2 = wave>>1).
// C/D layout [m74/m101]: col = lane&31, row = (reg&3)+8*(reg>>2)+4*(lane>>5).
// Gate: waves 0/1 compute dot(s_t[b], state[b]) from the SAME fragment
// registers the MFMA consumes (q-pair covers the full row) via dot2 +
// shfl_xor(32); sigmoid -> g_l. 2 lgkm-only barriers/step; sf/skg
// ping-pong prefetched at step TOP (full-step cover), wsv in update.
__global__ __launch_bounds__(512, 1) void scan_kernel(
    const unsigned short* __restrict__ sT2, const float* __restrict__ WsT,
    const float* __restrict__ vkey, const float* __restrict__ Uw,
    const float* __restrict__ Ub, const float* __restrict__ SK,
    float* __restrict__ h_out)
{
    __shared__ unsigned short AB[64 * 136];   // bf16 state, stride 136 (272B rows)
    __shared__ float g_l[64];
    __shared__ float wred[8];

    const int j    = blockIdx.x;
    const int tid  = threadIdx.x;        // 512
    const int wave = tid >> 6;           // 0..7
    const int lane = tid & 63;
    const int l32  = lane & 31;
    const int q    = lane >> 5;          // 0..1
    const int bt2  = wave & 1;           // b half
    const int nt2  = wave >> 1;          // n quarter
    const int n    = nt2 * 32 + l32;     // owned output column
    const int brow0= bt2 * 32 + l32;     // A-frag row (= gate row for waves 0/1)

    // ---- one-time: weight fragments -> 32 VGPRs (single bf16 plane, RNE) ----
    bf16x8 b_h[8];
    {
        const int k0 = q * 8;
        #pragma unroll
        for (int kc = 0; kc < 8; ++kc) {
            const float4* src = (const float4*)(Uw + n * 128 + kc * 16 + k0);
            const float4 v0 = src[0], v1 = src[1];
            const float xs[8] = {v0.x,v0.y,v0.z,v0.w, v1.x,v1.y,v1.z,v1.w};
            #pragma unroll
            for (int e = 0; e < 8; ++e) b_h[kc][e] = (short)f2bh(xs[e]);
        }
    }
    for (int i = tid; i < 64 * 136 / 2; i += 512) ((unsigned int*)AB)[i] = 0u;
    const float ubv = Ub[n] + vkey[j * 128 + n];

    // ---- per-thread invariant load offsets (bytes), computed once ----
    unsigned woffB[16];
    #pragma unroll
    for (int r = 0; r < 16; ++r) {
        const int brow = bt2*32 + 4*q + (r & 3) + 8*(r >> 2);
        woffB[r] = (unsigned)((brow * 128 + n) * 4);
    }
    const char* SKj = (const char*)SK + (size_t)j * 32768;
    // gate s-chunk base: sT2[t][kc*2+q][brow0][..] = t*16384 + (kc*2+q)*1024 + brow0*16
    const char* sfb = (const char*)sT2 + (size_t)q * 1024 + (size_t)brow0 * 16;
    const unsigned b4 = (unsigned)(brow0 * 4);

    // fp32 recurrence state (C layout), registers across steps
    float xprev[16];
    #pragma unroll
    for (int r = 0; r < 16; ++r) xprev[r] = 0.f;

    // ---- ping-pong gate inputs: set A = even t, set B = odd t ----
    uint4 sfA[8], sfB[8];
    float skgA = 0.f, skgB = 0.f;
    float wsv[16];
    {
        if (wave < 2) {
            #pragma unroll
            for (int kc = 0; kc < 8; ++kc)
                sfA[kc] = *(const uint4*)(sfb + kc * 2048);      // t = 0
            skgA = *(const float*)(SKj + b4);
        }
        const char* pW = (const char*)WsT;
        #pragma unroll
        for (int r = 0; r < 16; ++r) wsv[r] = *(const float*)(pW + woffB[r]);
    }
    __syncthreads();

    float inv_s = 1.f;                   // true mem = inv_s * bf16(state)

#define SCAN_STEP(T_CUR, SFc, SKGc, SFn, SKGn)                                 \
    {                                                                          \
        const int tn = (T_CUR < 127) ? (T_CUR) + 1 : 127;                      \
        /* prefetch t+1 gate inputs at TOP: full-step vmcnt cover */           \
        if (wave < 2) {                                                        \
            const char* pS = sfb + (size_t)tn * 16384;                         \
            _Pragma("unroll")                                                  \
            for (int kc = 0; kc < 8; ++kc)                                     \
                SFn[kc] = *(const uint4*)(pS + kc * 2048);                     \
            SKGn = *(const float*)(SKj + (size_t)tn * 256 + b4);               \
        }                                                                      \
        /* A-frags once: feed gate dot AND main MFMA */                        \
        uint4 w[8];                                                            \
        const unsigned short* arow = AB + brow0 * 136 + q * 8;                 \
        _Pragma("unroll")                                                      \
        for (int kc = 0; kc < 8; ++kc)                                         \
            w[kc] = *(const uint4*)(arow + kc * 16);                           \
        /* gate (waves 0/1): in-register dot, rows 0..31 / 32..63 */           \
        if (wave < 2) {                                                        \
            float d0 = 0.f, d1 = 0.f, d2 = 0.f, d3 = 0.f;                      \
            _Pragma("unroll")                                                  \
            for (int kc = 0; kc < 8; ++kc) {                                   \
                d0 = dot2bf(w[kc].x, SFc[kc].x, d0);                           \
                d1 = dot2bf(w[kc].y, SFc[kc].y, d1);                           \
                d2 = dot2bf(w[kc].z, SFc[kc].z, d2);                           \
                d3 = dot2bf(w[kc].w, SFc[kc].w, d3);                           \
            }                                                                  \
            float dd = (d0 + d1) + (d2 + d3);                                  \
            dd += __shfl_xor(dd, 32, 64);     /* combine q halves */           \
            if (q == 0) {                                                      \
                const float e = __expf(-fmaf(inv_s, dd, SKGc));                \
                g_l[brow0] = __builtin_amdgcn_rcpf(1.f + e);                   \
            }                                                                  \
        }                                                                      \
        /* main MFMA: acc = state(32b x 128m) . Uw(32n x 128m)^T */            \
        f32x16 acc0 = {0.f,0.f,0.f,0.f,0.f,0.f,0.f,0.f,                        \
                       0.f,0.f,0.f,0.f,0.f,0.f,0.f,0.f};                       \
        f32x16 acc1 = acc0;                                                    \
        _Pragma("unroll")                                                      \
        for (int kc = 0; kc < 8; ++kc) {                                       \
            const bf16x8 a = __builtin_bit_cast(bf16x8, w[kc]);                \
            if (kc & 1) acc1 = __builtin_amdgcn_mfma_f32_32x32x16_bf16(a, b_h[kc], acc1, 0, 0, 0); \
            else        acc0 = __builtin_amdgcn_mfma_f32_32x32x16_bf16(a, b_h[kc], acc0, 0, 0, 0); \
        }                                                                      \
        acc0 += acc1;                                                          \
        LDS_BARRIER();   /* B1: AB reads complete; g_l visible */              \
        /* update owned (b, n) cells in C layout */                            \
        const float4 gA = *(const float4*)(g_l + bt2*32 + 4*q + 0);            \
        const float4 gB = *(const float4*)(g_l + bt2*32 + 4*q + 8);            \
        const float4 gC = *(const float4*)(g_l + bt2*32 + 4*q + 16);           \
        const float4 gD = *(const float4*)(g_l + bt2*32 + 4*q + 24);           \
        const float gr[16] = {gA.x,gA.y,gA.z,gA.w, gB.x,gB.y,gB.z,gB.w,        \
                              gC.x,gC.y,gC.z,gC.w, gD.x,gD.y,gD.z,gD.w};       \
        float sq0 = 0.f, sq1 = 0.f;                                            \
        _Pragma("unroll")                                                      \
        for (int r = 0; r < 16; ++r) {                                         \
            const int brow = bt2*32 + 4*q + (r & 3) + 8*(r >> 2);              \
            float hr = fmaf(inv_s, acc0[r], ubv + wsv[r]);                     \
            hr = fmaxf(hr, 0.f);                          /* h_cand */         \
            const float x = fmaf(inv_s, xprev[r], gr[r] * hr);                 \
            xprev[r] = x;                                 /* fp32 recurrence */\
            AB[brow*136 + n] = (unsigned short)(__float_as_uint(x) >> 16);     \
            if (r & 1) sq1 = fmaf(x, x, sq1); else sq0 = fmaf(x, x, sq0);      \
        }                                                                      \
        /* wsv refetch for t+1 (use point is next update: ~1-step cover) */    \
        {                                                                      \
            const char* pW = (const char*)WsT + (size_t)tn * 32768;            \
            _Pragma("unroll")                                                  \
            for (int r = 0; r < 16; ++r)                                       \
                wsv[r] = *(const float*)(pW + woffB[r]);                       \
        }                                                                      \
        float ssq = sq0 + sq1;                                                 \
        ssq = dpp_xor1_add(ssq);                                               \
        ssq = dpp_xor2_add(ssq);                                               \
        ssq += __shfl_xor(ssq, 4, 64);                                         \
        ssq += __shfl_xor(ssq, 8, 64);                                         \
        ssq += __shfl_xor(ssq, 16, 64);                                        \
        ssq += __shfl_xor(ssq, 32, 64);                                        \
        if (lane == 0) wred[wave] = ssq;                                       \
        LDS_BARRIER();   /* B2: AB writes + wred visible (loads in flight) */  \
        const float4 w0 = *(const float4*)(wred);                              \
        const float4 w1 = *(const float4*)(wred + 4);                          \
        inv_s = __builtin_amdgcn_rsqf(w0.x+w0.y+w0.z+w0.w + w1.x+w1.y+w1.z+w1.w); \
    }

    for (int t = 0; t < 128; t += 2) {
        SCAN_STEP(t,     sfA, skgA, sfB, skgB)
        SCAN_STEP(t + 1, sfB, skgB, sfA, skgA)
    }
#undef SCAN_STEP

    // ---- h = inv * state (fp32 path), layout (b, j, m) ----
    #pragma unroll
    for (int r = 0; r < 16; ++r) {
        const int brow = bt2*32 + 4*q + (r & 3) + 8*(r >> 2);
        h_out[(brow*20 + j)*128 + n] = inv_s * xprev[r];
    }
}

// ---------------------------------------------------------------- final
__global__ __launch_bounds__(128) void final_kernel(
    const float* __restrict__ h, const float* __restrict__ qv,
    const float* __restrict__ a1v, const float* __restrict__ a2v,
    const float* __restrict__ Hw, const float* __restrict__ Hb,
    float* __restrict__ out)
{
    const int b   = blockIdx.x;
    const int tid = threadIdx.x;    // 128
    __shared__ float hb[20][128];
    __shared__ float ql[128];
    __shared__ float ul[128];
    __shared__ float pl[20];
    __shared__ float lgt[20];
    __shared__ float red1[2], red2[2];

    for (int jj = 0; jj < 20; ++jj) hb[jj][tid] = h[(b*20+jj)*128 + tid];
    ql[tid] = qv[b*128 + tid];
    __syncthreads();
    if (tid < 20) {
        float d = 0.f;
        for (int m = 0; m < 128; ++m) d += hb[tid][m] * ql[m];
        lgt[tid] = d;
    }
    __syncthreads();
    if (tid == 0) {
        float mx = lgt[0];
        for (int jj = 1; jj < 20; ++jj) mx = fmaxf(mx, lgt[jj]);
        float s = 0.f;
        for (int jj = 0; jj < 20; ++jj) { const float e = expf(lgt[jj]-mx); pl[jj] = e; s += e; }
        const float is = 1.f / s;
        for (int jj = 0; jj < 20; ++jj) pl[jj] *= is;
    }
    __syncthreads();
    float u = 0.f;
    for (int jj = 0; jj < 20; ++jj) u += pl[jj] * hb[jj][tid];
    ul[tid] = u;
    __syncthreads();
    float acc = ql[tid] + Hb[tid];
    const float4* hwr = (const float4*)(Hw + tid*128);
    for (int m4 = 0; m4 < 32; ++m4) {
        const float4 w = hwr[m4];
        acc += ul[m4*4]*w.x + ul[m4*4+1]*w.y + ul[m4*4+2]*w.z + ul[m4*4+3]*w.w;
    }
    const float r  = fmaxf(acc, 0.f);
    float y1 = r * a1v[b*128+tid];
    float y2 = r * a2v[b*128+tid];
    #pragma unroll
    for (int mask = 1; mask < 64; mask <<= 1) {
        y1 += __shfl_xor(y1, mask, 64);
        y2 += __shfl_xor(y2, mask, 64);
    }
    if ((tid & 63) == 0) { red1[tid>>6] = y1; red2[tid>>6] = y2; }
    __syncthreads();
    if (tid == 0) {
        const float z1 = red1[0] + red1[1];
        const float z2 = red2[0] + red2[1];
        const float mx = fmaxf(z1, z2);
        const float e1 = expf(z1-mx), e2 = expf(z2-mx);
        const float s  = e1 + e2;
        out[b*2+0] = e1 / s;
        out[b*2+1] = e2 / s;
    }
}

// ---------------------------------------------------------------- launch
extern "C" void kernel_launch(void* const* d_in, const int* in_sizes, int n_in,
                              void* d_out, int out_size, void* d_ws, size_t ws_size,
                              hipStream_t stream)
{
    const int*   ids  = (const int*)  d_in[0];
    const int*   ques = (const int*)  d_in[1];
    const int*   ans  = (const int*)  d_in[2];
    const float* E    = (const float*)d_in[3];
    const float* Uw   = (const float*)d_in[4];
    const float* Ubv  = (const float*)d_in[5];
    const float* Vw   = (const float*)d_in[6];
    const float* Vb   = (const float*)d_in[7];
    const float* Ww   = (const float*)d_in[8];
    const float* Wb   = (const float*)d_in[9];
    const float* sk   = (const float*)d_in[10];
    const float* Hw   = (const float*)d_in[11];
    const float* Hb   = (const float*)d_in[12];

    // workspace (floats): sT2 bf16[1048576] = 524288 floats | WsT 1048576 |
    //   vkey 2560 | qv/a1v/a2v 3*8192 | h 163840 | SK 163840   (~7.7 MB)
    float* ws   = (float*)d_ws;
    unsigned short* sT2 = (unsigned short*)ws;        // 1048576 ushort = 524288 floats
    float* WsT  = ws    + 524288;
    float* vkey = WsT   + 1048576;
    float* qv   = vkey  + 2560;
    float* a1v  = qv    + 8192;
    float* a2v  = a1v   + 8192;
    float* h    = a2v   + 8192;
    float* SK   = h     + 163840;

    prep_kernel<<<1108, 128, 0, stream>>>(ids, ques, ans, E, Ww, Wb, Vw, Vb, sk,
                                          sT2, WsT, vkey, qv, a1v, a2v, SK);
    scan_kernel<<<20, 512, 0, stream>>>(sT2, WsT, vkey, Uw, Ubv, SK, h);
    final_kernel<<<64, 128, 0, stream>>>(h, qv, a1v, a2v, Hw, Hb, (float*)d_out);
}

// Round 8
// 274.641 us; speedup vs baseline: 1.5627x; 1.5627x over previous
//
#include <hip/hip_runtime.h>
#include <math.h>

// EntNet forward on MI355X.
// Sizes: VOC=32000, MEM=128, NSLOTS=20, NSENT=128, MAXLEN=32, QLEN=16, ANSLEN=8, B=64
//
// R22 = R17 (best proven: scan 188us) + DPP reductions. R18-R21 lesson:
// structural gate rewrites all lose (serial phase placement / register
// pressure / scattered loads); only pure chain-latency cuts win.
//  - ssq reduce: 4x ds_swizzle shfl_xor (~150cy serial) -> 6x DPP
//    row_shr:1/2/4/8 + row_bcast:15/31 adds (~24cy); lane 63 writes wred.
//  - gate reduce: quad_perm x2 + shfl_xor(4) -> 3x DPP row_shr:1/2/4;
//    lanes (tid&7)==7 hold their 8-group sum (row_shr confined to 16-lane
//    rows; boundary lanes pull only own half - lane-traced).
// Zero new registers, zero new memory traffic vs R17.

typedef __attribute__((ext_vector_type(8)))  short bf16x8;
typedef __attribute__((ext_vector_type(16))) float f32x16;

__device__ __forceinline__ unsigned short f2bh(float x) {   // f32 -> bf16 RNE
    unsigned int u = __float_as_uint(x);
    u += 0x7FFFu + ((u >> 16) & 1u);
    return (unsigned short)(u >> 16);
}
// u32 holding two bf16 (little-endian): low 16 = element 2i, high = 2i+1
__device__ __forceinline__ float blo(unsigned int w) { return __uint_as_float(w << 16); }
__device__ __forceinline__ float bhi(unsigned int w) { return __uint_as_float(w & 0xFFFF0000u); }

// DPP add helper: x += dpp_move(x) with 0-fill (bound_ctrl=true).
// CTRL: row_shr:N = 0x110+N, row_bcast:15 = 0x142, row_bcast:31 = 0x143.
template<int CTRL>
__device__ __forceinline__ float dpp_add0(float x) {
    int y = __builtin_amdgcn_update_dpp(0, __float_as_int(x), CTRL, 0xF, 0xF, true);
    return x + __int_as_float(y);
}

// LDS-only workgroup barrier: waits own DS ops, does NOT drain vmcnt, so
// prefetched global loads (private register results) stay in flight.
#define LDS_BARRIER() do {                                   \
    asm volatile("s_waitcnt lgkmcnt(0)" ::: "memory");       \
    __builtin_amdgcn_s_barrier();                            \
    asm volatile("" ::: "memory");                           \
} while (0)

// ---------------------------------------------------------------- prep
__global__ __launch_bounds__(128) void prep_kernel(
    const int* __restrict__ ids, const int* __restrict__ ques, const int* __restrict__ ans,
    const float* __restrict__ E, const float* __restrict__ Ww, const float* __restrict__ Wb,
    const float* __restrict__ Vw, const float* __restrict__ Vb, const float* __restrict__ skeys,
    float* __restrict__ sT, float* __restrict__ WsT, float* __restrict__ vkey,
    float* __restrict__ qv, float* __restrict__ a1v, float* __restrict__ a2v,
    float* __restrict__ SK)
{
    const int bi  = blockIdx.x;
    const int tid = threadIdx.x;   // 128
    __shared__ float s_l[8][132];
    __shared__ float sk_l[20 * 132];
    __shared__ float k_l[128];
    if (bi < 1024) {
        const int b = bi >> 4;
        const int g = bi & 15;
        for (int r = tid; r < 2560; r += 128) sk_l[(r >> 7) * 132 + (r & 127)] = skeys[r];
        for (int tt = 0; tt < 8; ++tt) {
            const int t     = g * 8 + tt;
            const int token = ids[b * 4096 + t];
            const float v   = E[token * 128 + tid];
            s_l[tt][tid] = v;
            sT[(t * 64 + b) * 128 + tid] = v;         // layout (t, b, m)
        }
        __syncthreads();
        // Ws rows
        float acc[8];
        const float wbn = Wb[tid];
        #pragma unroll
        for (int i = 0; i < 8; ++i) acc[i] = wbn;
        const float4* wrow = (const float4*)(Ww + tid * 128);
        for (int m4 = 0; m4 < 32; ++m4) {
            const float4 w = wrow[m4];
            #pragma unroll
            for (int tt = 0; tt < 8; ++tt) {
                acc[tt] += s_l[tt][m4*4+0]*w.x + s_l[tt][m4*4+1]*w.y
                         + s_l[tt][m4*4+2]*w.z + s_l[tt][m4*4+3]*w.w;
            }
        }
        for (int tt = 0; tt < 8; ++tt)
            WsT[((g*8+tt) * 64 + b) * 128 + tid] = acc[tt];     // layout (t, b, n)
        // SK[j][t][b] = dot(s_t[b], skeys[j])  (gate key-dot, hoisted from scan)
        for (int idx = tid; idx < 160; idx += 128) {
            const int tt = idx / 20;
            const int jj = idx - tt * 20;
            float d = 0.f;
            for (int m = 0; m < 128; ++m) d += s_l[tt][m] * sk_l[jj * 132 + m];
            SK[(jj * 128 + (g*8 + tt)) * 64 + b] = d;
        }
    } else if (bi < 1044) {
        const int j = bi - 1024;
        k_l[tid] = skeys[j * 128 + tid];
        __syncthreads();
        float acc = Vb[tid];
        const float4* vrow = (const float4*)(Vw + tid * 128);
        for (int m4 = 0; m4 < 32; ++m4) {
            const float4 w = vrow[m4];
            acc += k_l[m4*4]*w.x + k_l[m4*4+1]*w.y + k_l[m4*4+2]*w.z + k_l[m4*4+3]*w.w;
        }
        vkey[j * 128 + tid] = acc;
    } else {
        const int b = bi - 1044;
        float sq = 0.f, s1 = 0.f, s2 = 0.f;
        for (int i = 0; i < 16; ++i) sq += E[ques[b*16+i] * 128 + tid];
        for (int i = 0; i < 8;  ++i) s1 += E[ans[(b*8+i)*2+0] * 128 + tid];
        for (int i = 0; i < 8;  ++i) s2 += E[ans[(b*8+i)*2+1] * 128 + tid];
        qv [b*128+tid] = sq * (1.f/16.f);
        a1v[b*128+tid] = s1 * 0.125f;
        a2v[b*128+tid] = s2 * 0.125f;
    }
}

// ---------------------------------------------------------------- scan (MFMA 32x32, bf16 state)
// One block per slot j. 512 threads = 8 waves, 2 waves/SIMD.
// Each wave owns ONE 32x32 C tile (bt2 = wave&1, nt2 = wave>>1).
// C/D layout [m74/m101]: col = lane&31, row = (reg&3)+8*(reg>>2)+4*(lane>>5).
// 2 lgkm-only barriers/step; sv/skv prefetch at step TOP (ping-pong regs,
// full-step vmcnt cover); wsv prefetch in update (~1-step cover).
// Reductions via DPP row_shr/row_bcast (see header note).
__global__ __launch_bounds__(512, 1) void scan_kernel(
    const float* __restrict__ sT, const float* __restrict__ WsT,
    const float* __restrict__ vkey, const float* __restrict__ Uw,
    const float* __restrict__ Ub, const float* __restrict__ SK,
    float* __restrict__ h_out)
{
    __shared__ unsigned short AB[64 * 136];   // bf16 state, stride 136 (272B rows)
    __shared__ float g_l[64];
    __shared__ float wred[8];

    const int j    = blockIdx.x;
    const int tid  = threadIdx.x;        // 512
    const int wave = tid >> 6;           // 0..7
    const int lane = tid & 63;
    const int l32  = lane & 31;
    const int q    = lane >> 5;          // 0..1
    const int bt2  = wave & 1;           // b half
    const int nt2  = wave >> 1;          // n quarter
    const int n    = nt2 * 32 + l32;     // owned output column
    const int gb   = tid >> 3;           // gate: batch row 0..63
    const int gm   = (tid & 7) * 16;     // gate: m-slice (16 bf16)

    // ---- one-time: weight fragments -> 32 VGPRs (single bf16 plane, RNE) ----
    bf16x8 b_h[8];
    {
        const int k0 = q * 8;
        #pragma unroll
        for (int kc = 0; kc < 8; ++kc) {
            const float4* src = (const float4*)(Uw + n * 128 + kc * 16 + k0);
            const float4 v0 = src[0], v1 = src[1];
            const float xs[8] = {v0.x,v0.y,v0.z,v0.w, v1.x,v1.y,v1.z,v1.w};
            #pragma unroll
            for (int e = 0; e < 8; ++e) b_h[kc][e] = (short)f2bh(xs[e]);
        }
    }
    for (int i = tid; i < 64 * 136 / 2; i += 512) ((unsigned int*)AB)[i] = 0u;
    const float ubv = Ub[n] + vkey[j * 128 + n];

    // ---- per-thread invariant load offsets (bytes), computed once ----
    unsigned woffB[16];
    #pragma unroll
    for (int r = 0; r < 16; ++r) {
        const int brow = bt2*32 + 4*q + (r & 3) + 8*(r >> 2);
        woffB[r] = (unsigned)((brow * 128 + n) * 4);
    }
    const unsigned soffB = (unsigned)((gb * 128 + gm) * 4);
    const unsigned koffB = (unsigned)(gb * 4);
    const char* SKj = (const char*)SK + (size_t)j * 32768;

    // fp32 recurrence state (C layout), registers across steps
    float xprev[16];
    #pragma unroll
    for (int r = 0; r < 16; ++r) xprev[r] = 0.f;

    // ---- ping-pong current-step globals: set A = even t, set B = odd t ----
    float4 svA0, svA1, svA2, svA3, svB0, svB1, svB2, svB3;
    float  skvA, skvB;
    float  wsv[16];
    {
        const float4* s4 = (const float4*)((const char*)sT + soffB);
        svA0 = s4[0]; svA1 = s4[1]; svA2 = s4[2]; svA3 = s4[3];
        skvA = *(const float*)(SKj + koffB);
        const char* pW = (const char*)WsT;
        #pragma unroll
        for (int r = 0; r < 16; ++r) wsv[r] = *(const float*)(pW + woffB[r]);
    }
    __syncthreads();

    float inv_s = 1.f;                   // true mem = inv_s * bf16(state)

#define SCAN_STEP(T_CUR, Sc0,Sc1,Sc2,Sc3,SKc, Sn0,Sn1,Sn2,Sn3,SKn)             \
    {                                                                          \
        const int tn = (T_CUR < 127) ? (T_CUR) + 1 : 127;                      \
        /* prefetch t+1 sv/skv at TOP: full-step vmcnt cover */                \
        {                                                                      \
            const float4* s4 = (const float4*)((const char*)sT + (size_t)tn * 32768 + soffB); \
            Sn0 = s4[0]; Sn1 = s4[1]; Sn2 = s4[2]; Sn3 = s4[3];                \
            SKn = *(const float*)(SKj + (size_t)tn * 256 + koffB);             \
        }                                                                      \
        /* gate: g[b] = sigmoid(inv*dot(s_t[b],mem[b]) + SK[j][t][b]) */       \
        {                                                                      \
            const uint4* u4 = (const uint4*)(AB + gb * 136 + gm);              \
            const uint4 w0 = u4[0], w1 = u4[1];                                \
            float a0 = Sc0.x*blo(w0.x), a1 = Sc0.y*bhi(w0.x);                  \
            float a2 = Sc0.z*blo(w0.y), a3 = Sc0.w*bhi(w0.y);                  \
            a0 = fmaf(Sc1.x, blo(w0.z), a0); a1 = fmaf(Sc1.y, bhi(w0.z), a1);  \
            a2 = fmaf(Sc1.z, blo(w0.w), a2); a3 = fmaf(Sc1.w, bhi(w0.w), a3);  \
            a0 = fmaf(Sc2.x, blo(w1.x), a0); a1 = fmaf(Sc2.y, bhi(w1.x), a1);  \
            a2 = fmaf(Sc2.z, blo(w1.y), a2); a3 = fmaf(Sc2.w, bhi(w1.y), a3);  \
            a0 = fmaf(Sc3.x, blo(w1.z), a0); a1 = fmaf(Sc3.y, bhi(w1.z), a1);  \
            a2 = fmaf(Sc3.z, blo(w1.w), a2); a3 = fmaf(Sc3.w, bhi(w1.w), a3);  \
            float d1 = (a0 + a1) + (a2 + a3);                                  \
            d1 = dpp_add0<0x111>(d1);  /* row_shr:1 */                         \
            d1 = dpp_add0<0x112>(d1);  /* row_shr:2 */                         \
            d1 = dpp_add0<0x114>(d1);  /* row_shr:4 -> lanes 7 mod 8 hold sum */ \
            if ((tid & 7) == 7) {                                              \
                const float e = __expf(-(inv_s * d1 + SKc));                   \
                g_l[gb] = __builtin_amdgcn_rcpf(1.f + e);                      \
            }                                                                  \
        }                                                                      \
        /* MFMA: acc = state(32b x 128m) . Uw(32n x 128m)^T */                 \
        f32x16 acc0 = {0.f,0.f,0.f,0.f,0.f,0.f,0.f,0.f,                        \
                       0.f,0.f,0.f,0.f,0.f,0.f,0.f,0.f};                       \
        f32x16 acc1 = acc0;                                                    \
        {                                                                      \
            const unsigned short* arow = AB + (bt2*32 + l32) * 136 + q * 8;    \
            _Pragma("unroll")                                                  \
            for (int kc = 0; kc < 8; ++kc) {                                   \
                const bf16x8 a = *(const bf16x8*)(arow + kc * 16);             \
                if (kc & 1) acc1 = __builtin_amdgcn_mfma_f32_32x32x16_bf16(a, b_h[kc], acc1, 0, 0, 0); \
                else        acc0 = __builtin_amdgcn_mfma_f32_32x32x16_bf16(a, b_h[kc], acc0, 0, 0, 0); \
            }                                                                  \
            acc0 += acc1;  /* merge before B1: frees 16 VGPRs for update */    \
        }                                                                      \
        LDS_BARRIER();   /* B1: AB reads complete; g_l visible */              \
        /* update owned (b, n) cells in C layout */                            \
        const float4 gA = *(const float4*)(g_l + bt2*32 + 4*q + 0);            \
        const float4 gB = *(const float4*)(g_l + bt2*32 + 4*q + 8);            \
        const float4 gC = *(const float4*)(g_l + bt2*32 + 4*q + 16);           \
        const float4 gD = *(const float4*)(g_l + bt2*32 + 4*q + 24);           \
        const float gr[16] = {gA.x,gA.y,gA.z,gA.w, gB.x,gB.y,gB.z,gB.w,        \
                              gC.x,gC.y,gC.z,gC.w, gD.x,gD.y,gD.z,gD.w};       \
        float sq0 = 0.f, sq1 = 0.f;                                            \
        _Pragma("unroll")                                                      \
        for (int r = 0; r < 16; ++r) {                                         \
            const int brow = bt2*32 + 4*q + (r & 3) + 8*(r >> 2);              \
            float hr = fmaf(inv_s, acc0[r], ubv + wsv[r]);                     \
            hr = fmaxf(hr, 0.f);                          /* h_cand */         \
            const float x = fmaf(inv_s, xprev[r], gr[r] * hr);                 \
            xprev[r] = x;                                 /* fp32 recurrence */\
            AB[brow*136 + n] = (unsigned short)(__float_as_uint(x) >> 16);     \
            if (r & 1) sq1 = fmaf(x, x, sq1); else sq0 = fmaf(x, x, sq0);      \
        }                                                                      \
        /* wsv refetch for t+1 (use point is next update: ~1-step cover) */    \
        {                                                                      \
            const char* pW = (const char*)WsT + (size_t)tn * 32768;            \
            _Pragma("unroll")                                                  \
            for (int r = 0; r < 16; ++r)                                       \
                wsv[r] = *(const float*)(pW + woffB[r]);                       \
        }                                                                      \
        /* ssq reduce: 6-op DPP chain, lane 63 holds the wave total */         \
        float ssq = sq0 + sq1;                                                 \
        ssq = dpp_add0<0x111>(ssq);    /* row_shr:1 */                         \
        ssq = dpp_add0<0x112>(ssq);    /* row_shr:2 */                         \
        ssq = dpp_add0<0x114>(ssq);    /* row_shr:4 */                         \
        ssq = dpp_add0<0x118>(ssq);    /* row_shr:8 -> lane15 of each row */   \
        ssq = dpp_add0<0x142>(ssq);    /* row_bcast:15 -> lane31/63 combine */ \
        ssq = dpp_add0<0x143>(ssq);    /* row_bcast:31 -> lane63 total */      \
        if (lane == 63) wred[wave] = ssq;                                      \
        LDS_BARRIER();   /* B2: AB writes + wred visible (loads in flight) */  \
        const float4 w0 = *(const float4*)(wred);                              \
        const float4 w1 = *(const float4*)(wred + 4);                          \
        inv_s = __builtin_amdgcn_rsqf(w0.x+w0.y+w0.z+w0.w + w1.x+w1.y+w1.z+w1.w); \
    }

    for (int t = 0; t < 128; t += 2) {
        SCAN_STEP(t,     svA0,svA1,svA2,svA3,skvA, svB0,svB1,svB2,svB3,skvB)
        SCAN_STEP(t + 1, svB0,svB1,svB2,svB3,skvB, svA0,svA1,svA2,svA3,skvA)
    }
#undef SCAN_STEP

    // ---- h = inv * state (fp32 path), layout (b, j, m) ----
    #pragma unroll
    for (int r = 0; r < 16; ++r) {
        const int brow = bt2*32 + 4*q + (r & 3) + 8*(r >> 2);
        h_out[(brow*20 + j)*128 + n] = inv_s * xprev[r];
    }
}

// ---------------------------------------------------------------- final
__global__ __launch_bounds__(128) void final_kernel(
    const float* __restrict__ h, const float* __restrict__ qv,
    const float* __restrict__ a1v, const float* __restrict__ a2v,
    const float* __restrict__ Hw, const float* __restrict__ Hb,
    float* __restrict__ out)
{
    const int b   = blockIdx.x;
    const int tid = threadIdx.x;    // 128
    __shared__ float hb[20][128];
    __shared__ float ql[128];
    __shared__ float ul[128];
    __shared__ float pl[20];
    __shared__ float lgt[20];
    __shared__ float red1[2], red2[2];

    for (int jj = 0; jj < 20; ++jj) hb[jj][tid] = h[(b*20+jj)*128 + tid];
    ql[tid] = qv[b*128 + tid];
    __syncthreads();
    if (tid < 20) {
        float d = 0.f;
        for (int m = 0; m < 128; ++m) d += hb[tid][m] * ql[m];
        lgt[tid] = d;
    }
    __syncthreads();
    if (tid == 0) {
        float mx = lgt[0];
        for (int jj = 1; jj < 20; ++jj) mx = fmaxf(mx, lgt[jj]);
        float s = 0.f;
        for (int jj = 0; jj < 20; ++jj) { const float e = expf(lgt[jj]-mx); pl[jj] = e; s += e; }
        const float is = 1.f / s;
        for (int jj = 0; jj < 20; ++jj) pl[jj] *= is;
    }
    __syncthreads();
    float u = 0.f;
    for (int jj = 0; jj < 20; ++jj) u += pl[jj] * hb[jj][tid];
    ul[tid] = u;
    __syncthreads();
    float acc = ql[tid] + Hb[tid];
    const float4* hwr = (const float4*)(Hw + tid*128);
    for (int m4 = 0; m4 < 32; ++m4) {
        const float4 w = hwr[m4];
        acc += ul[m4*4]*w.x + ul[m4*4+1]*w.y + ul[m4*4+2]*w.z + ul[m4*4+3]*w.w;
    }
    const float r  = fmaxf(acc, 0.f);
    float y1 = r * a1v[b*128+tid];
    float y2 = r * a2v[b*128+tid];
    #pragma unroll
    for (int mask = 1; mask < 64; mask <<= 1) {
        y1 += __shfl_xor(y1, mask, 64);
        y2 += __shfl_xor(y2, mask, 64);
    }
    if ((tid & 63) == 0) { red1[tid>>6] = y1; red2[tid>>6] = y2; }
    __syncthreads();
    if (tid == 0) {
        const float z1 = red1[0] + red1[1];
        const float z2 = red2[0] + red2[1];
        const float mx = fmaxf(z1, z2);
        const float e1 = expf(z1-mx), e2 = expf(z2-mx);
        const float s  = e1 + e2;
        out[b*2+0] = e1 / s;
        out[b*2+1] = e2 / s;
    }
}

// ---------------------------------------------------------------- launch
extern "C" void kernel_launch(void* const* d_in, const int* in_sizes, int n_in,
                              void* d_out, int out_size, void* d_ws, size_t ws_size,
                              hipStream_t stream)
{
    const int*   ids  = (const int*)  d_in[0];
    const int*   ques = (const int*)  d_in[1];
    const int*   ans  = (const int*)  d_in[2];
    const float* E    = (const float*)d_in[3];
    const float* Uw   = (const float*)d_in[4];
    const float* Ubv  = (const float*)d_in[5];
    const float* Vw   = (const float*)d_in[6];
    const float* Vb   = (const float*)d_in[7];
    const float* Ww   = (const float*)d_in[8];
    const float* Wb   = (const float*)d_in[9];
    const float* sk   = (const float*)d_in[10];
    const float* Hw   = (const float*)d_in[11];
    const float* Hb   = (const float*)d_in[12];

    // workspace (floats): sT 1M | WsT 1M | vkey 2560 | qv/a1v/a2v 3*8192 | h 163840 | SK 163840
    float* ws   = (float*)d_ws;
    float* sT   = ws;
    float* WsT  = sT  + 1048576;
    float* vkey = WsT + 1048576;
    float* qv   = vkey + 2560;
    float* a1v  = qv  + 8192;
    float* a2v  = a1v + 8192;
    float* h    = a2v + 8192;
    float* SK   = h   + 163840;

    prep_kernel<<<1108, 128, 0, stream>>>(ids, ques, ans, E, Ww, Wb, Vw, Vb, sk,
                                          sT, WsT, vkey, qv, a1v, a2v, SK);
    scan_kernel<<<20, 512, 0, stream>>>(sT, WsT, vkey, Uw, Ubv, SK, h);
    final_kernel<<<64, 128, 0, stream>>>(h, qv, a1v, a2v, Hw, Hb, (float*)d_out);
}

// Round 9
// 262.845 us; speedup vs baseline: 1.6328x; 1.0449x over previous
//
#include <hip/hip_runtime.h>
#include <math.h>

// EntNet forward on MI355X.
// Sizes: VOC=32000, MEM=128, NSLOTS=20, NSENT=128, MAXLEN=32, QLEN=16, ANSLEN=8, B=64
//
// R23 = R22 (best: scan 173us) + LDS-pipe cuts. DS-op census showed the
// LDS pipe ~70% busy per step; worst item = 16x ds_write_b16/thread for
// the state write-back (column-owned C layout).
//  (1) paired state writes: adjacent lanes own adjacent columns n/n+1;
//      one DPP xor1 exchange per element pair -> even lane writes rows
//      0..7 of the column-pair, odd lane rows 8..15, as packed 2xbf16
//      ds_write_b32. 16 b16 -> 8 b32 writes, all 64 lanes active
//      (bank-traced: 2-way aliasing only = free).
//  (2) sT plane stored bf16; gate dot via v_dot2_f32_bf16 (8 dot2 vs
//      16 unpack + 16 fma), sv ping-pong registers halved (R21's numeric
//      path, WITHOUT its register explosion), sT fetch traffic halved.
// Everything else byte-identical to R22 (DPP reductions, lgkm-only
// barriers, prefetch placement, MFMA block).

typedef __attribute__((ext_vector_type(8)))  short bf16x8;
typedef __attribute__((ext_vector_type(16))) float f32x16;

__device__ __forceinline__ unsigned short f2bh(float x) {   // f32 -> bf16 RNE
    unsigned int u = __float_as_uint(x);
    u += 0x7FFFu + ((u >> 16) & 1u);
    return (unsigned short)(u >> 16);
}
// pack two f32 -> u32 of two bf16 (truncation; fp32 recurrence carries precision)
__device__ __forceinline__ unsigned int packtr(float lo, float hi) {
    return (__float_as_uint(lo) >> 16) | (__float_as_uint(hi) & 0xFFFF0000u);
}
__device__ __forceinline__ float blo(unsigned int w) { return __uint_as_float(w << 16); }
__device__ __forceinline__ float bhi(unsigned int w) { return __uint_as_float(w & 0xFFFF0000u); }

#if __has_builtin(__builtin_amdgcn_fdot2_f32_bf16)
typedef __attribute__((ext_vector_type(2))) __bf16 bf16x2v;
__device__ __forceinline__ float dot2bf(unsigned int a, unsigned int b, float c) {
    return __builtin_amdgcn_fdot2_f32_bf16(
        __builtin_bit_cast(bf16x2v, a), __builtin_bit_cast(bf16x2v, b), c, false);
}
#else
__device__ __forceinline__ float dot2bf(unsigned int a, unsigned int b, float c) {
    return fmaf(bhi(a), bhi(b), fmaf(blo(a), blo(b), c));
}
#endif

// DPP add helper: x += dpp_move(x) with 0-fill (bound_ctrl=true).
// CTRL: row_shr:N = 0x110+N, row_bcast:15 = 0x142, row_bcast:31 = 0x143.
template<int CTRL>
__device__ __forceinline__ float dpp_add0(float x) {
    int y = __builtin_amdgcn_update_dpp(0, __float_as_int(x), CTRL, 0xF, 0xF, true);
    return x + __int_as_float(y);
}
// neighbor value via quad_perm xor1 (lane^1)
__device__ __forceinline__ float dpp_xor1_move(float x) {
    int y = __builtin_amdgcn_update_dpp(0, __float_as_int(x), 0xB1, 0xF, 0xF, true);
    return __int_as_float(y);
}

// LDS-only workgroup barrier: waits own DS ops, does NOT drain vmcnt, so
// prefetched global loads (private register results) stay in flight.
#define LDS_BARRIER() do {                                   \
    asm volatile("s_waitcnt lgkmcnt(0)" ::: "memory");       \
    __builtin_amdgcn_s_barrier();                            \
    asm volatile("" ::: "memory");                           \
} while (0)

// ---------------------------------------------------------------- prep
__global__ __launch_bounds__(128) void prep_kernel(
    const int* __restrict__ ids, const int* __restrict__ ques, const int* __restrict__ ans,
    const float* __restrict__ E, const float* __restrict__ Ww, const float* __restrict__ Wb,
    const float* __restrict__ Vw, const float* __restrict__ Vb, const float* __restrict__ skeys,
    unsigned short* __restrict__ sT2, float* __restrict__ WsT, float* __restrict__ vkey,
    float* __restrict__ qv, float* __restrict__ a1v, float* __restrict__ a2v,
    float* __restrict__ SK)
{
    const int bi  = blockIdx.x;
    const int tid = threadIdx.x;   // 128
    __shared__ float s_l[8][132];
    __shared__ float sk_l[20 * 132];
    __shared__ float k_l[128];
    if (bi < 1024) {
        const int b = bi >> 4;
        const int g = bi & 15;
        for (int r = tid; r < 2560; r += 128) sk_l[(r >> 7) * 132 + (r & 127)] = skeys[r];
        for (int tt = 0; tt < 8; ++tt) {
            const int t     = g * 8 + tt;
            const int token = ids[b * 4096 + t];
            const float v   = E[token * 128 + tid];
            s_l[tt][tid] = v;
            sT2[(t * 64 + b) * 128 + tid] = f2bh(v);   // bf16 plane (t, b, m)
        }
        __syncthreads();
        // Ws rows
        float acc[8];
        const float wbn = Wb[tid];
        #pragma unroll
        for (int i = 0; i < 8; ++i) acc[i] = wbn;
        const float4* wrow = (const float4*)(Ww + tid * 128);
        for (int m4 = 0; m4 < 32; ++m4) {
            const float4 w = wrow[m4];
            #pragma unroll
            for (int tt = 0; tt < 8; ++tt) {
                acc[tt] += s_l[tt][m4*4+0]*w.x + s_l[tt][m4*4+1]*w.y
                         + s_l[tt][m4*4+2]*w.z + s_l[tt][m4*4+3]*w.w;
            }
        }
        for (int tt = 0; tt < 8; ++tt)
            WsT[((g*8+tt) * 64 + b) * 128 + tid] = acc[tt];     // layout (t, b, n)
        // SK[j][t][b] = dot(s_t[b], skeys[j])  (gate key-dot, hoisted from scan)
        for (int idx = tid; idx < 160; idx += 128) {
            const int tt = idx / 20;
            const int jj = idx - tt * 20;
            float d = 0.f;
            for (int m = 0; m < 128; ++m) d += s_l[tt][m] * sk_l[jj * 132 + m];
            SK[(jj * 128 + (g*8 + tt)) * 64 + b] = d;
        }
    } else if (bi < 1044) {
        const int j = bi - 1024;
        k_l[tid] = skeys[j * 128 + tid];
        __syncthreads();
        float acc = Vb[tid];
        const float4* vrow = (const float4*)(Vw + tid * 128);
        for (int m4 = 0; m4 < 32; ++m4) {
            const float4 w = vrow[m4];
            acc += k_l[m4*4]*w.x + k_l[m4*4+1]*w.y + k_l[m4*4+2]*w.z + k_l[m4*4+3]*w.w;
        }
        vkey[j * 128 + tid] = acc;
    } else {
        const int b = bi - 1044;
        float sq = 0.f, s1 = 0.f, s2 = 0.f;
        for (int i = 0; i < 16; ++i) sq += E[ques[b*16+i] * 128 + tid];
        for (int i = 0; i < 8;  ++i) s1 += E[ans[(b*8+i)*2+0] * 128 + tid];
        for (int i = 0; i < 8;  ++i) s2 += E[ans[(b*8+i)*2+1] * 128 + tid];
        qv [b*128+tid] = sq * (1.f/16.f);
        a1v[b*128+tid] = s1 * 0.125f;
        a2v[b*128+tid] = s2 * 0.125f;
    }
}

// ---------------------------------------------------------------- scan (MFMA 32x32, bf16 state)
// One block per slot j. 512 threads = 8 waves, 2 waves/SIMD.
// Each wave owns ONE 32x32 C tile (bt2 = wave&1, nt2 = wave>>1).
// C/D layout [m74/m101]: col = lane&31, row = (reg&3)+8*(reg>>2)+4*(lane>>5).
// 2 lgkm-only barriers/step; sv/skv prefetch at step TOP (ping-pong regs,
// full-step vmcnt cover); wsv prefetch in update (~1-step cover).
// DPP reductions; paired b32 state writes; bf16 gate via dot2.
__global__ __launch_bounds__(512, 1) void scan_kernel(
    const unsigned short* __restrict__ sT2, const float* __restrict__ WsT,
    const float* __restrict__ vkey, const float* __restrict__ Uw,
    const float* __restrict__ Ub, const float* __restrict__ SK,
    float* __restrict__ h_out)
{
    __shared__ unsigned short AB[64 * 136];   // bf16 state, stride 136 (272B rows)
    __shared__ float g_l[64];
    __shared__ float wred[8];

    const int j    = blockIdx.x;
    const int tid  = threadIdx.x;        // 512
    const int wave = tid >> 6;           // 0..7
    const int lane = tid & 63;
    const int l32  = lane & 31;
    const int q    = lane >> 5;          // 0..1
    const int bt2  = wave & 1;           // b half
    const int nt2  = wave >> 1;          // n quarter
    const int n    = nt2 * 32 + l32;     // owned output column
    const int gb   = tid >> 3;           // gate: batch row 0..63
    const int gm   = (tid & 7) * 16;     // gate: m-slice (16 bf16)
    const bool evenl = ((l32 & 1) == 0); // column-pair parity

    // ---- one-time: weight fragments -> 32 VGPRs (single bf16 plane, RNE) ----
    bf16x8 b_h[8];
    {
        const int k0 = q * 8;
        #pragma unroll
        for (int kc = 0; kc < 8; ++kc) {
            const float4* src = (const float4*)(Uw + n * 128 + kc * 16 + k0);
            const float4 v0 = src[0], v1 = src[1];
            const float xs[8] = {v0.x,v0.y,v0.z,v0.w, v1.x,v1.y,v1.z,v1.w};
            #pragma unroll
            for (int e = 0; e < 8; ++e) b_h[kc][e] = (short)f2bh(xs[e]);
        }
    }
    for (int i = tid; i < 64 * 136 / 2; i += 512) ((unsigned int*)AB)[i] = 0u;
    const float ubv = Ub[n] + vkey[j * 128 + n];

    // ---- per-thread invariant load offsets (bytes), computed once ----
    unsigned woffB[16];
    #pragma unroll
    for (int r = 0; r < 16; ++r) {
        const int brow = bt2*32 + 4*q + (r & 3) + 8*(r >> 2);
        woffB[r] = (unsigned)((brow * 128 + n) * 4);
    }
    const unsigned soffB = (unsigned)((gb * 128 + gm) * 2);   // bf16 plane
    const unsigned koffB = (unsigned)(gb * 4);
    const char* SKj = (const char*)SK + (size_t)j * 32768;
    // paired state-write base: row = bt2*32 + 4q + parity*16, colpair byte = (n&~1)*2
    unsigned* const wdst = (unsigned*)((char*)AB
        + (bt2*32 + 4*q + ((l32 & 1) << 4)) * 272 + ((n & ~1) * 2));

    // fp32 recurrence state (C layout), registers across steps
    float xprev[16];
    #pragma unroll
    for (int r = 0; r < 16; ++r) xprev[r] = 0.f;

    // ---- ping-pong current-step globals: set A = even t, set B = odd t ----
    uint4 svA0, svA1, svB0, svB1;      // 16 bf16 of s_t[gb][gm..gm+15]
    float skvA, skvB;
    float wsv[16];
    {
        const char* pS = (const char*)sT2 + soffB;
        svA0 = *(const uint4*)(pS); svA1 = *(const uint4*)(pS + 16);
        skvA = *(const float*)(SKj + koffB);
        const char* pW = (const char*)WsT;
        #pragma unroll
        for (int r = 0; r < 16; ++r) wsv[r] = *(const float*)(pW + woffB[r]);
    }
    __syncthreads();

    float inv_s = 1.f;                   // true mem = inv_s * bf16(state)

#define SCAN_STEP(T_CUR, Sc0,Sc1,SKc, Sn0,Sn1,SKn)                             \
    {                                                                          \
        const int tn = (T_CUR < 127) ? (T_CUR) + 1 : 127;                      \
        /* prefetch t+1 sv/skv at TOP: full-step vmcnt cover */                \
        {                                                                      \
            const char* pS = (const char*)sT2 + (size_t)tn * 16384 + soffB;    \
            Sn0 = *(const uint4*)(pS); Sn1 = *(const uint4*)(pS + 16);         \
            SKn = *(const float*)(SKj + (size_t)tn * 256 + koffB);             \
        }                                                                      \
        /* gate: g[b] = sigmoid(inv*dot(s_t[b],mem[b]) + SK[j][t][b]) */       \
        {                                                                      \
            const uint4* u4 = (const uint4*)(AB + gb * 136 + gm);              \
            const uint4 w0 = u4[0], w1 = u4[1];                                \
            float d0 = dot2bf(w0.x, Sc0.x, 0.f);                               \
            float d1 = dot2bf(w0.y, Sc0.y, 0.f);                               \
            float d2 = dot2bf(w0.z, Sc0.z, 0.f);                               \
            float d3 = dot2bf(w0.w, Sc0.w, 0.f);                               \
            d0 = dot2bf(w1.x, Sc1.x, d0);                                      \
            d1 = dot2bf(w1.y, Sc1.y, d1);                                      \
            d2 = dot2bf(w1.z, Sc1.z, d2);                                      \
            d3 = dot2bf(w1.w, Sc1.w, d3);                                      \
            float dg = (d0 + d1) + (d2 + d3);                                  \
            dg = dpp_add0<0x111>(dg);  /* row_shr:1 */                         \
            dg = dpp_add0<0x112>(dg);  /* row_shr:2 */                         \
            dg = dpp_add0<0x114>(dg);  /* row_shr:4 -> lanes 7 mod 8 */        \
            if ((tid & 7) == 7) {                                              \
                const float e = __expf(-(inv_s * dg + SKc));                   \
                g_l[gb] = __builtin_amdgcn_rcpf(1.f + e);                      \
            }                                                                  \
        }                                                                      \
        /* MFMA: acc = state(32b x 128m) . Uw(32n x 128m)^T */                 \
        f32x16 acc0 = {0.f,0.f,0.f,0.f,0.f,0.f,0.f,0.f,                        \
                       0.f,0.f,0.f,0.f,0.f,0.f,0.f,0.f};                       \
        f32x16 acc1 = acc0;                                                    \
        {                                                                      \
            const unsigned short* arow = AB + (bt2*32 + l32) * 136 + q * 8;    \
            _Pragma("unroll")                                                  \
            for (int kc = 0; kc < 8; ++kc) {                                   \
                const bf16x8 a = *(const bf16x8*)(arow + kc * 16);             \
                if (kc & 1) acc1 = __builtin_amdgcn_mfma_f32_32x32x16_bf16(a, b_h[kc], acc1, 0, 0, 0); \
                else        acc0 = __builtin_amdgcn_mfma_f32_32x32x16_bf16(a, b_h[kc], acc0, 0, 0, 0); \
            }                                                                  \
            acc0 += acc1;  /* merge before B1: frees 16 VGPRs for update */    \
        }                                                                      \
        LDS_BARRIER();   /* B1: AB reads complete; g_l visible */              \
        /* update owned (b, n) cells in C layout */                            \
        const float4 gA = *(const float4*)(g_l + bt2*32 + 4*q + 0);            \
        const float4 gB = *(const float4*)(g_l + bt2*32 + 4*q + 8);            \
        const float4 gC = *(const float4*)(g_l + bt2*32 + 4*q + 16);           \
        const float4 gD = *(const float4*)(g_l + bt2*32 + 4*q + 24);           \
        const float gr[16] = {gA.x,gA.y,gA.z,gA.w, gB.x,gB.y,gB.z,gB.w,        \
                              gC.x,gC.y,gC.z,gC.w, gD.x,gD.y,gD.z,gD.w};       \
        float xv[16];                                                          \
        float sq0 = 0.f, sq1 = 0.f;                                            \
        _Pragma("unroll")                                                      \
        for (int r = 0; r < 16; ++r) {                                         \
            float hr = fmaf(inv_s, acc0[r], ubv + wsv[r]);                     \
            hr = fmaxf(hr, 0.f);                          /* h_cand */         \
            const float x = fmaf(inv_s, xprev[r], gr[r] * hr);                 \
            xprev[r] = x; xv[r] = x;                      /* fp32 recurrence */\
            if (r & 1) sq1 = fmaf(x, x, sq1); else sq0 = fmaf(x, x, sq0);      \
        }                                                                      \
        /* paired state write-back: 8x ds_write_b32, all lanes active */       \
        _Pragma("unroll")                                                      \
        for (int i = 0; i < 8; ++i) {                                          \
            const float xa = xv[i];                                            \
            const float xb = xv[i + 8];                                        \
            const float sa = dpp_xor1_move(xa);                                \
            const float sb = dpp_xor1_move(xb);                                \
            const float lo = evenl ? xa : sb;                                  \
            const float hi = evenl ? sa : xb;                                  \
            wdst[((i & 3) + 8 * (i >> 2)) * 68] = packtr(lo, hi);              \
        }                                                                      \
        /* wsv refetch for t+1 (use point is next update: ~1-step cover) */    \
        {                                                                      \
            const char* pW = (const char*)WsT + (size_t)tn * 32768;            \
            _Pragma("unroll")                                                  \
            for (int r = 0; r < 16; ++r)                                       \
                wsv[r] = *(const float*)(pW + woffB[r]);                       \
        }                                                                      \
        /* ssq reduce: 6-op DPP chain, lane 63 holds the wave total */         \
        float ssq = sq0 + sq1;                                                 \
        ssq = dpp_add0<0x111>(ssq);    /* row_shr:1 */                         \
        ssq = dpp_add0<0x112>(ssq);    /* row_shr:2 */                         \
        ssq = dpp_add0<0x114>(ssq);    /* row_shr:4 */                         \
        ssq = dpp_add0<0x118>(ssq);    /* row_shr:8 -> lane15 of each row */   \
        ssq = dpp_add0<0x142>(ssq);    /* row_bcast:15 -> lane31/63 combine */ \
        ssq = dpp_add0<0x143>(ssq);    /* row_bcast:31 -> lane63 total */      \
        if (lane == 63) wred[wave] = ssq;                                      \
        LDS_BARRIER();   /* B2: AB writes + wred visible (loads in flight) */  \
        const float4 w0 = *(const float4*)(wred);                              \
        const float4 w1 = *(const float4*)(wred + 4);                          \
        inv_s = __builtin_amdgcn_rsqf(w0.x+w0.y+w0.z+w0.w + w1.x+w1.y+w1.z+w1.w); \
    }

    for (int t = 0; t < 128; t += 2) {
        SCAN_STEP(t,     svA0,svA1,skvA, svB0,svB1,skvB)
        SCAN_STEP(t + 1, svB0,svB1,skvB, svA0,svA1,skvA)
    }
#undef SCAN_STEP

    // ---- h = inv * state (fp32 path), layout (b, j, m) ----
    #pragma unroll
    for (int r = 0; r < 16; ++r) {
        const int brow = bt2*32 + 4*q + (r & 3) + 8*(r >> 2);
        h_out[(brow*20 + j)*128 + n] = inv_s * xprev[r];
    }
}

// ---------------------------------------------------------------- final
__global__ __launch_bounds__(128) void final_kernel(
    const float* __restrict__ h, const float* __restrict__ qv,
    const float* __restrict__ a1v, const float* __restrict__ a2v,
    const float* __restrict__ Hw, const float* __restrict__ Hb,
    float* __restrict__ out)
{
    const int b   = blockIdx.x;
    const int tid = threadIdx.x;    // 128
    __shared__ float hb[20][128];
    __shared__ float ql[128];
    __shared__ float ul[128];
    __shared__ float pl[20];
    __shared__ float lgt[20];
    __shared__ float red1[2], red2[2];

    for (int jj = 0; jj < 20; ++jj) hb[jj][tid] = h[(b*20+jj)*128 + tid];
    ql[tid] = qv[b*128 + tid];
    __syncthreads();
    if (tid < 20) {
        float d = 0.f;
        for (int m = 0; m < 128; ++m) d += hb[tid][m] * ql[m];
        lgt[tid] = d;
    }
    __syncthreads();
    if (tid == 0) {
        float mx = lgt[0];
        for (int jj = 1; jj < 20; ++jj) mx = fmaxf(mx, lgt[jj]);
        float s = 0.f;
        for (int jj = 0; jj < 20; ++jj) { const float e = expf(lgt[jj]-mx); pl[jj] = e; s += e; }
        const float is = 1.f / s;
        for (int jj = 0; jj < 20; ++jj) pl[jj] *= is;
    }
    __syncthreads();
    float u = 0.f;
    for (int jj = 0; jj < 20; ++jj) u += pl[jj] * hb[jj][tid];
    ul[tid] = u;
    __syncthreads();
    float acc = ql[tid] + Hb[tid];
    const float4* hwr = (const float4*)(Hw + tid*128);
    for (int m4 = 0; m4 < 32; ++m4) {
        const float4 w = hwr[m4];
        acc += ul[m4*4]*w.x + ul[m4*4+1]*w.y + ul[m4*4+2]*w.z + ul[m4*4+3]*w.w;
    }
    const float r  = fmaxf(acc, 0.f);
    float y1 = r * a1v[b*128+tid];
    float y2 = r * a2v[b*128+tid];
    #pragma unroll
    for (int mask = 1; mask < 64; mask <<= 1) {
        y1 += __shfl_xor(y1, mask, 64);
        y2 += __shfl_xor(y2, mask, 64);
    }
    if ((tid & 63) == 0) { red1[tid>>6] = y1; red2[tid>>6] = y2; }
    __syncthreads();
    if (tid == 0) {
        const float z1 = red1[0] + red1[1];
        const float z2 = red2[0] + red2[1];
        const float mx = fmaxf(z1, z2);
        const float e1 = expf(z1-mx), e2 = expf(z2-mx);
        const float s  = e1 + e2;
        out[b*2+0] = e1 / s;
        out[b*2+1] = e2 / s;
    }
}

// ---------------------------------------------------------------- launch
extern "C" void kernel_launch(void* const* d_in, const int* in_sizes, int n_in,
                              void* d_out, int out_size, void* d_ws, size_t ws_size,
                              hipStream_t stream)
{
    const int*   ids  = (const int*)  d_in[0];
    const int*   ques = (const int*)  d_in[1];
    const int*   ans  = (const int*)  d_in[2];
    const float* E    = (const float*)d_in[3];
    const float* Uw   = (const float*)d_in[4];
    const float* Ubv  = (const float*)d_in[5];
    const float* Vw   = (const float*)d_in[6];
    const float* Vb   = (const float*)d_in[7];
    const float* Ww   = (const float*)d_in[8];
    const float* Wb   = (const float*)d_in[9];
    const float* sk   = (const float*)d_in[10];
    const float* Hw   = (const float*)d_in[11];
    const float* Hb   = (const float*)d_in[12];

    // workspace (floats): sT2 bf16[1048576] = 524288 floats | WsT 1048576 |
    //   vkey 2560 | qv/a1v/a2v 3*8192 | h 163840 | SK 163840   (~7.7 MB)
    float* ws   = (float*)d_ws;
    unsigned short* sT2 = (unsigned short*)ws;        // 1048576 ushort = 524288 floats
    float* WsT  = ws    + 524288;
    float* vkey = WsT   + 1048576;
    float* qv   = vkey  + 2560;
    float* a1v  = qv    + 8192;
    float* a2v  = a1v   + 8192;
    float* h    = a2v   + 8192;
    float* SK   = h     + 163840;

    prep_kernel<<<1108, 128, 0, stream>>>(ids, ques, ans, E, Ww, Wb, Vw, Vb, sk,
                                          sT2, WsT, vkey, qv, a1v, a2v, SK);
    scan_kernel<<<20, 512, 0, stream>>>(sT2, WsT, vkey, Uw, Ubv, SK, h);
    final_kernel<<<64, 128, 0, stream>>>(h, qv, a1v, a2v, Hw, Hb, (float*)d_out);
}

// Round 12
// 260.485 us; speedup vs baseline: 1.6476x; 1.0091x over previous
//
#include <hip/hip_runtime.h>
#include <math.h>

// EntNet forward on MI355X.
// Sizes: VOC=32000, MEM=128, NSLOTS=20, NSENT=128, MAXLEN=32, QLEN=16, ANSLEN=8, B=64
//
// R24c = R24 with __builtin_amdgcn_perm replaced by the R23-proven
// shift/or pack (hedge: R24 never ran — two container failures in a row;
// this removes the only never-before-executed builtin while keeping the
// pk-f32 VALU-cut theory intact).
//
// R24 = R23 (best: scan 158us) + VALU-issue cuts. Counters show the scan
// is VALU-issue-bound (~54% VALUBusy on the 20 active CUs; LDS ~50%,
// MFMA ~16%). gfx950 has packed-FP32 VOP3P (v_pk_fma/add/mul_f32):
//  (1) update loop on float2 via __builtin_elementwise_fma/max -> pk ops;
//  (2) acc0+=acc1 merge as vector add (16 -> 8);
//  (3) ssq accumulated as float2 pk-fma, one horizontal add at the end.
// All arithmetic bit-identical to R23. Structure/barriers/prefetch/gate
// unchanged. Non-scan time is a constant ~104us of harness dispatches.

typedef __attribute__((ext_vector_type(8)))  short bf16x8;
typedef __attribute__((ext_vector_type(16))) float f32x16;
typedef __attribute__((ext_vector_type(2)))  float f32x2;

__device__ __forceinline__ unsigned short f2bh(float x) {   // f32 -> bf16 RNE
    unsigned int u = __float_as_uint(x);
    u += 0x7FFFu + ((u >> 16) & 1u);
    return (unsigned short)(u >> 16);
}
// pack two f32 -> u32 of two bf16 (truncation; fp32 recurrence carries precision)
__device__ __forceinline__ unsigned int packtr(float lo, float hi) {
    return (__float_as_uint(lo) >> 16) | (__float_as_uint(hi) & 0xFFFF0000u);
}
__device__ __forceinline__ float blo(unsigned int w) { return __uint_as_float(w << 16); }
__device__ __forceinline__ float bhi(unsigned int w) { return __uint_as_float(w & 0xFFFF0000u); }

// packed-f32 helpers (lower to v_pk_* on gfx90a+/gfx950)
__device__ __forceinline__ f32x2 pkfma(f32x2 a, f32x2 b, f32x2 c) {
    return __builtin_elementwise_fma(a, b, c);
}
__device__ __forceinline__ f32x2 pkmax0(f32x2 a) {
    return __builtin_elementwise_max(a, (f32x2){0.f, 0.f});
}

#if __has_builtin(__builtin_amdgcn_fdot2_f32_bf16)
typedef __attribute__((ext_vector_type(2))) __bf16 bf16x2v;
__device__ __forceinline__ float dot2bf(unsigned int a, unsigned int b, float c) {
    return __builtin_amdgcn_fdot2_f32_bf16(
        __builtin_bit_cast(bf16x2v, a), __builtin_bit_cast(bf16x2v, b), c, false);
}
#else
__device__ __forceinline__ float dot2bf(unsigned int a, unsigned int b, float c) {
    return fmaf(bhi(a), bhi(b), fmaf(blo(a), blo(b), c));
}
#endif

// DPP add helper: x += dpp_move(x) with 0-fill (bound_ctrl=true).
// CTRL: row_shr:N = 0x110+N, row_bcast:15 = 0x142, row_bcast:31 = 0x143.
template<int CTRL>
__device__ __forceinline__ float dpp_add0(float x) {
    int y = __builtin_amdgcn_update_dpp(0, __float_as_int(x), CTRL, 0xF, 0xF, true);
    return x + __int_as_float(y);
}
// neighbor value via quad_perm xor1 (lane^1)
__device__ __forceinline__ float dpp_xor1_move(float x) {
    int y = __builtin_amdgcn_update_dpp(0, __float_as_int(x), 0xB1, 0xF, 0xF, true);
    return __int_as_float(y);
}

// LDS-only workgroup barrier: waits own DS ops, does NOT drain vmcnt, so
// prefetched global loads (private register results) stay in flight.
#define LDS_BARRIER() do {                                   \
    asm volatile("s_waitcnt lgkmcnt(0)" ::: "memory");       \
    __builtin_amdgcn_s_barrier();                            \
    asm volatile("" ::: "memory");                           \
} while (0)

// ---------------------------------------------------------------- prep
__global__ __launch_bounds__(128) void prep_kernel(
    const int* __restrict__ ids, const int* __restrict__ ques, const int* __restrict__ ans,
    const float* __restrict__ E, const float* __restrict__ Ww, const float* __restrict__ Wb,
    const float* __restrict__ Vw, const float* __restrict__ Vb, const float* __restrict__ skeys,
    unsigned short* __restrict__ sT2, float* __restrict__ WsT, float* __restrict__ vkey,
    float* __restrict__ qv, float* __restrict__ a1v, float* __restrict__ a2v,
    float* __restrict__ SK)
{
    const int bi  = blockIdx.x;
    const int tid = threadIdx.x;   // 128
    __shared__ float s_l[8][132];
    __shared__ float sk_l[20 * 132];
    __shared__ float k_l[128];
    if (bi < 1024) {
        const int b = bi >> 4;
        const int g = bi & 15;
        for (int r = tid; r < 2560; r += 128) sk_l[(r >> 7) * 132 + (r & 127)] = skeys[r];
        for (int tt = 0; tt < 8; ++tt) {
            const int t     = g * 8 + tt;
            const int token = ids[b * 4096 + t];
            const float v   = E[token * 128 + tid];
            s_l[tt][tid] = v;
            sT2[(t * 64 + b) * 128 + tid] = f2bh(v);   // bf16 plane (t, b, m)
        }
        __syncthreads();
        // Ws rows
        float acc[8];
        const float wbn = Wb[tid];
        #pragma unroll
        for (int i = 0; i < 8; ++i) acc[i] = wbn;
        const float4* wrow = (const float4*)(Ww + tid * 128);
        for (int m4 = 0; m4 < 32; ++m4) {
            const float4 w = wrow[m4];
            #pragma unroll
            for (int tt = 0; tt < 8; ++tt) {
                acc[tt] += s_l[tt][m4*4+0]*w.x + s_l[tt][m4*4+1]*w.y
                         + s_l[tt][m4*4+2]*w.z + s_l[tt][m4*4+3]*w.w;
            }
        }
        for (int tt = 0; tt < 8; ++tt)
            WsT[((g*8+tt) * 64 + b) * 128 + tid] = acc[tt];     // layout (t, b, n)
        // SK[j][t][b] = dot(s_t[b], skeys[j])  (gate key-dot, hoisted from scan)
        for (int idx = tid; idx < 160; idx += 128) {
            const int tt = idx / 20;
            const int jj = idx - tt * 20;
            float d = 0.f;
            for (int m = 0; m < 128; ++m) d += s_l[tt][m] * sk_l[jj * 132 + m];
            SK[(jj * 128 + (g*8 + tt)) * 64 + b] = d;
        }
    } else if (bi < 1044) {
        const int j = bi - 1024;
        k_l[tid] = skeys[j * 128 + tid];
        __syncthreads();
        float acc = Vb[tid];
        const float4* vrow = (const float4*)(Vw + tid * 128);
        for (int m4 = 0; m4 < 32; ++m4) {
            const float4 w = vrow[m4];
            acc += k_l[m4*4]*w.x + k_l[m4*4+1]*w.y + k_l[m4*4+2]*w.z + k_l[m4*4+3]*w.w;
        }
        vkey[j * 128 + tid] = acc;
    } else {
        const int b = bi - 1044;
        float sq = 0.f, s1 = 0.f, s2 = 0.f;
        for (int i = 0; i < 16; ++i) sq += E[ques[b*16+i] * 128 + tid];
        for (int i = 0; i < 8;  ++i) s1 += E[ans[(b*8+i)*2+0] * 128 + tid];
        for (int i = 0; i < 8;  ++i) s2 += E[ans[(b*8+i)*2+1] * 128 + tid];
        qv [b*128+tid] = sq * (1.f/16.f);
        a1v[b*128+tid] = s1 * 0.125f;
        a2v[b*128+tid] = s2 * 0.125f;
    }
}

// ---------------------------------------------------------------- scan (MFMA 32x32, bf16 state)
// One block per slot j. 512 threads = 8 waves, 2 waves/SIMD.
// Each wave owns ONE 32x32 C tile (bt2 = wave&1, nt2 = wave>>1).
// C/D layout [m74/m101]: col = lane&31, row = (reg&3)+8*(reg>>2)+4*(lane>>5).
// 2 lgkm-only barriers/step; sv/skv prefetch at step TOP (ping-pong regs,
// full-step vmcnt cover); wsv prefetch in update (~1-step cover).
// DPP reductions; paired b32 state writes; bf16 gate via dot2; pk-f32 update.
__global__ __launch_bounds__(512, 1) void scan_kernel(
    const unsigned short* __restrict__ sT2, const float* __restrict__ WsT,
    const float* __restrict__ vkey, const float* __restrict__ Uw,
    const float* __restrict__ Ub, const float* __restrict__ SK,
    float* __restrict__ h_out)
{
    __shared__ unsigned short AB[64 * 136];   // bf16 state, stride 136 (272B rows)
    __shared__ float g_l[64];
    __shared__ float wred[8];

    const int j    = blockIdx.x;
    const int tid  = threadIdx.x;        // 512
    const int wave = tid >> 6;           // 0..7
    const int lane = tid & 63;
    const int l32  = lane & 31;
    const int q    = lane >> 5;          // 0..1
    const int bt2  = wave & 1;           // b half
    const int nt2  = wave >> 1;          // n quarter
    const int n    = nt2 * 32 + l32;     // owned output column
    const int gb   = tid >> 3;           // gate: batch row 0..63
    const int gm   = (tid & 7) * 16;     // gate: m-slice (16 bf16)
    const bool evenl = ((l32 & 1) == 0); // column-pair parity

    // ---- one-time: weight fragments -> 32 VGPRs (single bf16 plane, RNE) ----
    bf16x8 b_h[8];
    {
        const int k0 = q * 8;
        #pragma unroll
        for (int kc = 0; kc < 8; ++kc) {
            const float4* src = (const float4*)(Uw + n * 128 + kc * 16 + k0);
            const float4 v0 = src[0], v1 = src[1];
            const float xs[8] = {v0.x,v0.y,v0.z,v0.w, v1.x,v1.y,v1.z,v1.w};
            #pragma unroll
            for (int e = 0; e < 8; ++e) b_h[kc][e] = (short)f2bh(xs[e]);
        }
    }
    for (int i = tid; i < 64 * 136 / 2; i += 512) ((unsigned int*)AB)[i] = 0u;
    const float ubv = Ub[n] + vkey[j * 128 + n];

    // ---- per-thread invariant load offsets (bytes), computed once ----
    unsigned woffB[16];
    #pragma unroll
    for (int r = 0; r < 16; ++r) {
        const int brow = bt2*32 + 4*q + (r & 3) + 8*(r >> 2);
        woffB[r] = (unsigned)((brow * 128 + n) * 4);
    }
    const unsigned soffB = (unsigned)((gb * 128 + gm) * 2);   // bf16 plane
    const unsigned koffB = (unsigned)(gb * 4);
    const char* SKj = (const char*)SK + (size_t)j * 32768;
    // paired state-write base: row = bt2*32 + 4q + parity*16, colpair byte = (n&~1)*2
    unsigned* const wdst = (unsigned*)((char*)AB
        + (bt2*32 + 4*q + ((l32 & 1) << 4)) * 272 + ((n & ~1) * 2));

    // fp32 recurrence state (C layout, f32x2 pairs p=(r0/2): {even r, odd r})
    f32x2 xprev2[8];
    #pragma unroll
    for (int p = 0; p < 8; ++p) xprev2[p] = (f32x2){0.f, 0.f};
#define XV(k) ((k) & 1 ? xprev2[(k) >> 1].y : xprev2[(k) >> 1].x)

    // ---- ping-pong current-step globals: set A = even t, set B = odd t ----
    uint4 svA0, svA1, svB0, svB1;      // 16 bf16 of s_t[gb][gm..gm+15]
    float skvA, skvB;
    float wsv[16];
    {
        const char* pS = (const char*)sT2 + soffB;
        svA0 = *(const uint4*)(pS); svA1 = *(const uint4*)(pS + 16);
        skvA = *(const float*)(SKj + koffB);
        const char* pW = (const char*)WsT;
        #pragma unroll
        for (int r = 0; r < 16; ++r) wsv[r] = *(const float*)(pW + woffB[r]);
    }
    __syncthreads();

    float inv_s = 1.f;                   // true mem = inv_s * bf16(state)

#define SCAN_STEP(T_CUR, Sc0,Sc1,SKc, Sn0,Sn1,SKn)                             \
    {                                                                          \
        const int tn = (T_CUR < 127) ? (T_CUR) + 1 : 127;                      \
        /* prefetch t+1 sv/skv at TOP: full-step vmcnt cover */                \
        {                                                                      \
            const char* pS = (const char*)sT2 + (size_t)tn * 16384 + soffB;    \
            Sn0 = *(const uint4*)(pS); Sn1 = *(const uint4*)(pS + 16);         \
            SKn = *(const float*)(SKj + (size_t)tn * 256 + koffB);             \
        }                                                                      \
        /* gate: g[b] = sigmoid(inv*dot(s_t[b],mem[b]) + SK[j][t][b]) */       \
        {                                                                      \
            const uint4* u4 = (const uint4*)(AB + gb * 136 + gm);              \
            const uint4 w0 = u4[0], w1 = u4[1];                                \
            float d0 = dot2bf(w0.x, Sc0.x, 0.f);                               \
            float d1 = dot2bf(w0.y, Sc0.y, 0.f);                               \
            float d2 = dot2bf(w0.z, Sc0.z, 0.f);                               \
            float d3 = dot2bf(w0.w, Sc0.w, 0.f);                               \
            d0 = dot2bf(w1.x, Sc1.x, d0);                                      \
            d1 = dot2bf(w1.y, Sc1.y, d1);                                      \
            d2 = dot2bf(w1.z, Sc1.z, d2);                                      \
            d3 = dot2bf(w1.w, Sc1.w, d3);                                      \
            float dg = (d0 + d1) + (d2 + d3);                                  \
            dg = dpp_add0<0x111>(dg);  /* row_shr:1 */                         \
            dg = dpp_add0<0x112>(dg);  /* row_shr:2 */                         \
            dg = dpp_add0<0x114>(dg);  /* row_shr:4 -> lanes 7 mod 8 */        \
            if ((tid & 7) == 7) {                                              \
                const float e = __expf(-(inv_s * dg + SKc));                   \
                g_l[gb] = __builtin_amdgcn_rcpf(1.f + e);                      \
            }                                                                  \
        }                                                                      \
        /* MFMA: acc = state(32b x 128m) . Uw(32n x 128m)^T */                 \
        f32x16 acc0 = {0.f,0.f,0.f,0.f,0.f,0.f,0.f,0.f,                        \
                       0.f,0.f,0.f,0.f,0.f,0.f,0.f,0.f};                       \
        f32x16 acc1 = acc0;                                                    \
        {                                                                      \
            const unsigned short* arow = AB + (bt2*32 + l32) * 136 + q * 8;    \
            _Pragma("unroll")                                                  \
            for (int kc = 0; kc < 8; ++kc) {                                   \
                const bf16x8 a = *(const bf16x8*)(arow + kc * 16);             \
                if (kc & 1) acc1 = __builtin_amdgcn_mfma_f32_32x32x16_bf16(a, b_h[kc], acc1, 0, 0, 0); \
                else        acc0 = __builtin_amdgcn_mfma_f32_32x32x16_bf16(a, b_h[kc], acc0, 0, 0, 0); \
            }                                                                  \
            acc0 += acc1;  /* merge before B1 (vector add -> v_pk_add_f32) */  \
        }                                                                      \
        LDS_BARRIER();   /* B1: AB reads complete; g_l visible */              \
        /* update owned (b, n) cells in C layout — packed f32 pairs */         \
        const float4 gA = *(const float4*)(g_l + bt2*32 + 4*q + 0);            \
        const float4 gB = *(const float4*)(g_l + bt2*32 + 4*q + 8);            \
        const float4 gC = *(const float4*)(g_l + bt2*32 + 4*q + 16);           \
        const float4 gD = *(const float4*)(g_l + bt2*32 + 4*q + 24);           \
        const f32x2 g2[8] = {{gA.x,gA.y},{gA.z,gA.w},{gB.x,gB.y},{gB.z,gB.w},  \
                             {gC.x,gC.y},{gC.z,gC.w},{gD.x,gD.y},{gD.z,gD.w}}; \
        const f32x2 inv2 = {inv_s, inv_s};                                     \
        const f32x2 ub2  = {ubv, ubv};                                         \
        f32x2 ssqv = {0.f, 0.f};                                               \
        _Pragma("unroll")                                                      \
        for (int p = 0; p < 8; ++p) {                                          \
            const f32x2 am = {acc0[2*p], acc0[2*p+1]};                         \
            const f32x2 wu = (f32x2){wsv[2*p], wsv[2*p+1]} + ub2;              \
            f32x2 hr = pkfma(inv2, am, wu);                                    \
            hr = pkmax0(hr);                              /* h_cand */         \
            const f32x2 x = pkfma(inv2, xprev2[p], hr * g2[p]);                \
            xprev2[p] = x;                                /* fp32 recurrence */\
            ssqv = pkfma(x, x, ssqv);                                          \
        }                                                                      \
        /* paired state write-back: 8x ds_write_b32 (R23-proven pack) */       \
        _Pragma("unroll")                                                      \
        for (int i = 0; i < 8; ++i) {                                          \
            const float xa = XV(i);                                            \
            const float xb = XV(i + 8);                                        \
            const float sa = dpp_xor1_move(xa);                                \
            const float sb = dpp_xor1_move(xb);                                \
            const float lo = evenl ? xa : sb;                                  \
            const float hi = evenl ? sa : xb;                                  \
            wdst[((i & 3) + 8 * (i >> 2)) * 68] = packtr(lo, hi);              \
        }                                                                      \
        /* wsv refetch for t+1 (use point is next update: ~1-step cover) */    \
        {                                                                      \
            const char* pW = (const char*)WsT + (size_t)tn * 32768;            \
            _Pragma("unroll")                                                  \
            for (int r = 0; r < 16; ++r)                                       \
                wsv[r] = *(const float*)(pW + woffB[r]);                       \
        }                                                                      \
        /* ssq reduce: 6-op DPP chain, lane 63 holds the wave total */         \
        float ssq = ssqv.x + ssqv.y;                                           \
        ssq = dpp_add0<0x111>(ssq);    /* row_shr:1 */                         \
        ssq = dpp_add0<0x112>(ssq);    /* row_shr:2 */                         \
        ssq = dpp_add0<0x114>(ssq);    /* row_shr:4 */                         \
        ssq = dpp_add0<0x118>(ssq);    /* row_shr:8 -> lane15 of each row */   \
        ssq = dpp_add0<0x142>(ssq);    /* row_bcast:15 -> lane31/63 combine */ \
        ssq = dpp_add0<0x143>(ssq);    /* row_bcast:31 -> lane63 total */      \
        if (lane == 63) wred[wave] = ssq;                                      \
        LDS_BARRIER();   /* B2: AB writes + wred visible (loads in flight) */  \
        const float4 w0 = *(const float4*)(wred);                              \
        const float4 w1 = *(const float4*)(wred + 4);                          \
        const float4 ws4 = w0 + w1;                                            \
        inv_s = __builtin_amdgcn_rsqf((ws4.x + ws4.y) + (ws4.z + ws4.w));      \
    }

    for (int t = 0; t < 128; t += 2) {
        SCAN_STEP(t,     svA0,svA1,skvA, svB0,svB1,skvB)
        SCAN_STEP(t + 1, svB0,svB1,skvB, svA0,svA1,skvA)
    }
#undef SCAN_STEP

    // ---- h = inv * state (fp32 path), layout (b, j, m) ----
    #pragma unroll
    for (int r = 0; r < 16; ++r) {
        const int brow = bt2*32 + 4*q + (r & 3) + 8*(r >> 2);
        h_out[(brow*20 + j)*128 + n] = inv_s * XV(r);
    }
#undef XV
}

// ---------------------------------------------------------------- final
__global__ __launch_bounds__(128) void final_kernel(
    const float* __restrict__ h, const float* __restrict__ qv,
    const float* __restrict__ a1v, const float* __restrict__ a2v,
    const float* __restrict__ Hw, const float* __restrict__ Hb,
    float* __restrict__ out)
{
    const int b   = blockIdx.x;
    const int tid = threadIdx.x;    // 128
    __shared__ float hb[20][128];
    __shared__ float ql[128];
    __shared__ float ul[128];
    __shared__ float pl[20];
    __shared__ float lgt[20];
    __shared__ float red1[2], red2[2];

    for (int jj = 0; jj < 20; ++jj) hb[jj][tid] = h[(b*20+jj)*128 + tid];
    ql[tid] = qv[b*128 + tid];
    __syncthreads();
    if (tid < 20) {
        float d = 0.f;
        for (int m = 0; m < 128; ++m) d += hb[tid][m] * ql[m];
        lgt[tid] = d;
    }
    __syncthreads();
    if (tid == 0) {
        float mx = lgt[0];
        for (int jj = 1; jj < 20; ++jj) mx = fmaxf(mx, lgt[jj]);
        float s = 0.f;
        for (int jj = 0; jj < 20; ++jj) { const float e = expf(lgt[jj]-mx); pl[jj] = e; s += e; }
        const float is = 1.f / s;
        for (int jj = 0; jj < 20; ++jj) pl[jj] *= is;
    }
    __syncthreads();
    float u = 0.f;
    for (int jj = 0; jj < 20; ++jj) u += pl[jj] * hb[jj][tid];
    ul[tid] = u;
    __syncthreads();
    float acc = ql[tid] + Hb[tid];
    const float4* hwr = (const float4*)(Hw + tid*128);
    for (int m4 = 0; m4 < 32; ++m4) {
        const float4 w = hwr[m4];
        acc += ul[m4*4]*w.x + ul[m4*4+1]*w.y + ul[m4*4+2]*w.z + ul[m4*4+3]*w.w;
    }
    const float r  = fmaxf(acc, 0.f);
    float y1 = r * a1v[b*128+tid];
    float y2 = r * a2v[b*128+tid];
    #pragma unroll
    for (int mask = 1; mask < 64; mask <<= 1) {
        y1 += __shfl_xor(y1, mask, 64);
        y2 += __shfl_xor(y2, mask, 64);
    }
    if ((tid & 63) == 0) { red1[tid>>6] = y1; red2[tid>>6] = y2; }
    __syncthreads();
    if (tid == 0) {
        const float z1 = red1[0] + red1[1];
        const float z2 = red2[0] + red2[1];
        const float mx = fmaxf(z1, z2);
        const float e1 = expf(z1-mx), e2 = expf(z2-mx);
        const float s  = e1 + e2;
        out[b*2+0] = e1 / s;
        out[b*2+1] = e2 / s;
    }
}

// ---------------------------------------------------------------- launch
extern "C" void kernel_launch(void* const* d_in, const int* in_sizes, int n_in,
                              void* d_out, int out_size, void* d_ws, size_t ws_size,
                              hipStream_t stream)
{
    const int*   ids  = (const int*)  d_in[0];
    const int*   ques = (const int*)  d_in[1];
    const int*   ans  = (const int*)  d_in[2];
    const float* E    = (const float*)d_in[3];
    const float* Uw   = (const float*)d_in[4];
    const float* Ubv  = (const float*)d_in[5];
    const float* Vw   = (const float*)d_in[6];
    const float* Vb   = (const float*)d_in[7];
    const float* Ww   = (const float*)d_in[8];
    const float* Wb   = (const float*)d_in[9];
    const float* sk   = (const float*)d_in[10];
    const float* Hw   = (const float*)d_in[11];
    const float* Hb   = (const float*)d_in[12];

    // workspace (floats): sT2 bf16[1048576] = 524288 floats | WsT 1048576 |
    //   vkey 2560 | qv/a1v/a2v 3*8192 | h 163840 | SK 163840   (~7.7 MB)
    float* ws   = (float*)d_ws;
    unsigned short* sT2 = (unsigned short*)ws;        // 1048576 ushort = 524288 floats
    float* WsT  = ws    + 524288;
    float* vkey = WsT   + 1048576;
    float* qv   = vkey  + 2560;
    float* a1v  = qv    + 8192;
    float* a2v  = a1v   + 8192;
    float* h    = a2v   + 8192;
    float* SK   = h     + 163840;

    prep_kernel<<<1108, 128, 0, stream>>>(ids, ques, ans, E, Ww, Wb, Vw, Vb, sk,
                                          sT2, WsT, vkey, qv, a1v, a2v, SK);
    scan_kernel<<<20, 512, 0, stream>>>(sT2, WsT, vkey, Uw, Ubv, SK, h);
    final_kernel<<<64, 128, 0, stream>>>(h, qv, a1v, a2v, Hw, Hb, (float*)d_out);
}